// Round 9
// baseline (703.156 us; speedup 1.0000x reference)
//
#include <hip/hip_runtime.h>

#define B_ 8
#define C_ 512
#define T_ 8192
#define TOK_ 256
#define CD_ 768

typedef __attribute__((ext_vector_type(8))) short bf16x8;
typedef __attribute__((ext_vector_type(4))) float f32x4;

__device__ __forceinline__ unsigned short f2bf(float f){
  union { float f; unsigned u; } v; v.f = f;
  return (unsigned short)((v.u + 0x7FFFu + ((v.u >> 16) & 1u)) >> 16);
}
__device__ __forceinline__ float bf2f(unsigned short h){
  union { unsigned u; float f; } v; v.u = ((unsigned)h) << 16;
  return v.f;
}

// ---------------- A: merged prep: ctx layernorm + Wq pack + Wk/Wv pack ----------------
__global__ __launch_bounds__(256) void prep(const float* __restrict__ ctx,
    const float* __restrict__ cg_, const float* __restrict__ cb_,
    const float* __restrict__ Wq, const float* __restrict__ Wk, const float* __restrict__ Wv,
    unsigned short* __restrict__ ctx_nb, unsigned short* __restrict__ wq_pk,
    unsigned short* __restrict__ wkv_pk){
  __shared__ float rs[4][2];
  const int bid = blockIdx.x;
  const int tid = threadIdx.x;
  if (bid < 2048){
    // ---- ctx_ln row ----
    const float* p = ctx + (size_t)bid * CD_;
    float s1 = 0.f, s2 = 0.f;
    for (int i = tid; i < CD_; i += 256){ float v = p[i]; s1 += v; s2 += v * v; }
    #pragma unroll
    for (int o = 32; o > 0; o >>= 1){ s1 += __shfl_xor(s1, o); s2 += __shfl_xor(s2, o); }
    if ((tid & 63) == 0){ rs[tid >> 6][0] = s1; rs[tid >> 6][1] = s2; }
    __syncthreads();
    s1 = rs[0][0] + rs[1][0] + rs[2][0] + rs[3][0];
    s2 = rs[0][1] + rs[1][1] + rs[2][1] + rs[3][1];
    float m = s1 / (float)CD_;
    float var = s2 / (float)CD_ - m * m;
    float rstd = rsqrtf(var + 1e-5f);
    unsigned short* q = ctx_nb + (size_t)bid * CD_;
    for (int i = tid; i < CD_; i += 256) q[i] = f2bf((p[i] - m) * rstd * cg_[i] + cb_[i]);
  } else if (bid < 2176){
    // ---- pack Wq: slot=(kk*32+nt)*64+ln ; elem j = Wq[nt*16+(ln&15)][kk*32+(ln>>4)*8+j]
    int slot = (bid - 2048) * 256 + tid;             // 0..32767
    int ln = slot & 63, nt = (slot >> 6) & 31, kk = slot >> 11;
    int n  = nt * 16 + (ln & 15);
    int k0 = kk * 32 + (ln >> 4) * 8;
    bf16x8 v;
    #pragma unroll
    for (int j = 0; j < 8; j++) v[j] = (short)f2bf(Wq[(size_t)n * C_ + k0 + j]);
    *(bf16x8*)&wq_pk[(size_t)slot * 8] = v;
  } else {
    // ---- pack Wk|Wv: slot=((h*24+kk)*8+nt)*64+ln ; nt<4 -> Wk, nt>=4 -> Wv
    int slot = (bid - 2176) * 256 + tid;             // 0..98303
    int ln = slot & 63, nt = (slot >> 6) & 7;
    int kkh = slot >> 9;
    int kk = kkh % 24, h = kkh / 24;
    const float* W = (nt < 4) ? Wk : Wv;
    int row = h * 64 + (nt & 3) * 16 + (ln & 15);
    int k0 = kk * 32 + (ln >> 4) * 8;
    bf16x8 v;
    #pragma unroll
    for (int j = 0; j < 8; j++) v[j] = (short)f2bf(W[(size_t)row * CD_ + k0 + j]);
    *(bf16x8*)&wkv_pk[(size_t)slot * 8] = v;
  }
}

// ---------------- A2: fused context pipeline: KV-proj (MFMA) + mask + softmax + attn (MFMA) ----------------
// one block per (b,h); 256 threads = 4 waves; wave w owns ctx rows [64w,64w+64)
__global__ __launch_bounds__(256) void ctx_attn(const unsigned short* __restrict__ ctx_nb,
    const unsigned short* __restrict__ wkv_pk,
    const float* __restrict__ bk, const float* __restrict__ bv,
    const int* __restrict__ mask, unsigned short* __restrict__ apk){
  __shared__ __align__(16) char smem[75776];
  unsigned short* a_st  = (unsigned short*)smem;            // [2][8192] staging (aliases p_lds)
  unsigned short* p_lds = (unsigned short*)smem;            // [64][256] bf16, d-major
  unsigned short* v_lds = (unsigned short*)(smem + 32768);  // [64][256] bf16, e-major
  unsigned short* al    = (unsigned short*)(smem + 65536);  // [64][64] attn bf16
  float* wred = (float*)(smem + 73728);                     // [4][64]
  int* msk_l  = (int*)(smem + 74752);                       // [256]

  const int tid = threadIdx.x;
  const int b = blockIdx.x >> 3, h = blockIdx.x & 7;
  msk_l[tid] = mask[b * 256 + tid];

  const unsigned short* cb = ctx_nb + (size_t)b * 256 * CD_;
  const int w = tid >> 6, ln = tid & 63, lc = ln & 15, lk = ln >> 4;

  // stage kk=0 (row = tid, 32 k-values = 4 x bf16x8)
  {
    const bf16x8* src = (const bf16x8*)(cb + (size_t)tid * CD_);
    #pragma unroll
    for (int s = 0; s < 4; s++){
      bf16x8 vv = src[s];
      *(bf16x8*)&a_st[(tid * 32 + s * 8) ^ ((tid & 7) << 3)] = vv;
    }
  }
  const bf16x8* wv_ = (const bf16x8*)wkv_pk;
  const size_t wbase = (size_t)h * 24 * 8 * 64;
  f32x4 acc[4][8];
  #pragma unroll
  for (int i = 0; i < 4; i++)
    #pragma unroll
    for (int j = 0; j < 8; j++) acc[i][j] = (f32x4){0.f,0.f,0.f,0.f};
  bf16x8 bbuf[2][8];
  #pragma unroll
  for (int nt = 0; nt < 8; nt++) bbuf[0][nt] = wv_[wbase + (size_t)(0 * 8 + nt) * 64 + ln];
  __syncthreads();

  // GEMM: M=256 (n), N=128 (64 k-d | 64 v-e), K=768; reg-staged prefetch
  for (int kk = 0; kk < 24; kk++){
    int cur = kk & 1;
    bf16x8 nx[4];
    if (kk < 23){
      const bf16x8* src = (const bf16x8*)(cb + (size_t)tid * CD_ + (kk + 1) * 32);
      #pragma unroll
      for (int s = 0; s < 4; s++) nx[s] = src[s];
      #pragma unroll
      for (int nt = 0; nt < 8; nt++)
        bbuf[cur ^ 1][nt] = wv_[wbase + (size_t)((kk + 1) * 8 + nt) * 64 + ln];
    }
    bf16x8 af[4];
    #pragma unroll
    for (int mt = 0; mt < 4; mt++){
      int row = w * 64 + mt * 16 + lc;
      af[mt] = *(const bf16x8*)&a_st[cur * 8192 + ((row * 32 + lk * 8) ^ ((row & 7) << 3))];
    }
    #pragma unroll
    for (int mt = 0; mt < 4; mt++)
      #pragma unroll
      for (int nt = 0; nt < 8; nt++)
        acc[mt][nt] = __builtin_amdgcn_mfma_f32_16x16x32_bf16(af[mt], bbuf[cur][nt], acc[mt][nt], 0, 0, 0);
    if (kk < 23){
      unsigned short* dst = a_st + (cur ^ 1) * 8192;
      #pragma unroll
      for (int s = 0; s < 4; s++)
        *(bf16x8*)&dst[(tid * 32 + s * 8) ^ ((tid & 7) << 3)] = nx[s];
    }
    __syncthreads();
  }

  // bias + mask
  float bia[8];
  #pragma unroll
  for (int nt = 0; nt < 8; nt++)
    bia[nt] = (nt < 4) ? bk[h * 64 + nt * 16 + lc] : bv[h * 64 + (nt - 4) * 16 + lc];
  bool mk[4][4];
  #pragma unroll
  for (int mt = 0; mt < 4; mt++)
    #pragma unroll
    for (int r = 0; r < 4; r++)
      mk[mt][r] = msk_l[w * 64 + mt * 16 + lk * 4 + r] != 0;

  // softmax over n for k-part (nt 0..3): column d = nt*16+lc
  float cred[4];
  #pragma unroll
  for (int nt = 0; nt < 4; nt++){
    float mx = -3.402823466e38f;
    #pragma unroll
    for (int mt = 0; mt < 4; mt++)
      #pragma unroll
      for (int r = 0; r < 4; r++)
        if (mk[mt][r]) mx = fmaxf(mx, acc[mt][nt][r] + bia[nt]);
    mx = fmaxf(mx, __shfl_xor(mx, 16));
    mx = fmaxf(mx, __shfl_xor(mx, 32));
    cred[nt] = mx;
  }
  if (lk == 0){
    #pragma unroll
    for (int nt = 0; nt < 4; nt++) wred[w * 64 + nt * 16 + lc] = cred[nt];
  }
  __syncthreads();
  float gmx[4];
  #pragma unroll
  for (int nt = 0; nt < 4; nt++){
    int d = nt * 16 + lc;
    gmx[nt] = fmaxf(fmaxf(wred[d], wred[64 + d]), fmaxf(wred[128 + d], wred[192 + d]));
  }
  __syncthreads();
  #pragma unroll
  for (int nt = 0; nt < 4; nt++){
    float s = 0.f;
    #pragma unroll
    for (int mt = 0; mt < 4; mt++)
      #pragma unroll
      for (int r = 0; r < 4; r++){
        float p = mk[mt][r] ? expf(acc[mt][nt][r] + bia[nt] - gmx[nt]) : 0.f;
        acc[mt][nt][r] = p;
        s += p;
      }
    s += __shfl_xor(s, 16);
    s += __shfl_xor(s, 32);
    cred[nt] = s;
  }
  if (lk == 0){
    #pragma unroll
    for (int nt = 0; nt < 4; nt++) wred[w * 64 + nt * 16 + lc] = cred[nt];
  }
  __syncthreads();
  float ginv[4];
  #pragma unroll
  for (int nt = 0; nt < 4; nt++){
    int d = nt * 16 + lc;
    float s = wred[d] + wred[64 + d] + wred[128 + d] + wred[192 + d];
    ginv[nt] = 1.0f / fmaxf(s, 1e-30f);
  }
  // write p_lds[d][n], v_lds[e][n] (bf16, row-swizzled) — safe: all GEMM reads done
  #pragma unroll
  for (int nt = 0; nt < 4; nt++){
    int d = nt * 16 + lc;
    #pragma unroll
    for (int mt = 0; mt < 4; mt++)
      #pragma unroll
      for (int r = 0; r < 4; r++){
        int n = w * 64 + mt * 16 + lk * 4 + r;
        p_lds[(d * 256 + n) ^ ((d & 7) << 3)] = f2bf(acc[mt][nt][r] * ginv[nt]);
      }
  }
  #pragma unroll
  for (int nt = 4; nt < 8; nt++){
    int e = (nt - 4) * 16 + lc;
    #pragma unroll
    for (int mt = 0; mt < 4; mt++)
      #pragma unroll
      for (int r = 0; r < 4; r++){
        int n = w * 64 + mt * 16 + lk * 4 + r;
        float vv = mk[mt][r] ? (acc[mt][nt][r] + bia[nt]) : 0.f;
        v_lds[(e * 256 + n) ^ ((e & 7) << 3)] = f2bf(vv);
      }
  }
  __syncthreads();

  // attn = p^T @ v : M=64(d) N=64(e) K=256(n); wave w does d-rows [16w,16w+16)
  f32x4 acc2[4];
  #pragma unroll
  for (int i = 0; i < 4; i++) acc2[i] = (f32x4){0.f,0.f,0.f,0.f};
  #pragma unroll
  for (int kk = 0; kk < 8; kk++){
    int d = w * 16 + lc;
    bf16x8 pa = *(const bf16x8*)&p_lds[(d * 256 + kk * 32 + lk * 8) ^ ((d & 7) << 3)];
    #pragma unroll
    for (int nt2 = 0; nt2 < 4; nt2++){
      int e = nt2 * 16 + lc;
      bf16x8 vb = *(const bf16x8*)&v_lds[(e * 256 + kk * 32 + lk * 8) ^ ((e & 7) << 3)];
      acc2[nt2] = __builtin_amdgcn_mfma_f32_16x16x32_bf16(pa, vb, acc2[nt2], 0, 0, 0);
    }
  }
  #pragma unroll
  for (int nt2 = 0; nt2 < 4; nt2++)
    #pragma unroll
    for (int r = 0; r < 4; r++)
      al[(w * 16 + lk * 4 + r) * 64 + nt2 * 16 + lc] = f2bf(acc2[nt2][r]);
  __syncthreads();

  // pack apk: slot=(kk*4+nt)*64+l2 ; elem j = al[(kk*32+(l2>>4)*8+j)*64 + nt*16+(l2&15)]
  #pragma unroll
  for (int s2 = 0; s2 < 2; s2++){
    int slot = s2 * 256 + tid;           // 0..511
    int l2 = slot & 63, nt = (slot >> 6) & 3, kk = slot >> 8;
    int e = nt * 16 + (l2 & 15), d0 = kk * 32 + (l2 >> 4) * 8;
    bf16x8 v;
    #pragma unroll
    for (int j = 0; j < 8; j++) v[j] = (short)al[(d0 + j) * 64 + e];
    *(bf16x8*)&apk[((size_t)(b * 8 + h) * 512 + slot) * 8] = v;
  }
}

// ---------------- B: fused LN -> Q-proj (MFMA) -> softmax -> PV^T (MFMA) -> residual ----------------
// 64-token tile, 512 threads = 8 waves (wr = t-half 0/1, wc = 128-col slice 0..3)
__global__ __launch_bounds__(512, 4) void fused_main(const float* __restrict__ x,
    const float* __restrict__ g, const float* __restrict__ bl,
    const unsigned short* __restrict__ wq_pk, const float* __restrict__ bq,
    const unsigned short* __restrict__ attn_pk, float* __restrict__ out){
  __shared__ unsigned short a_lds[64 * 512];   // bf16 A-tile (swizzled); reused for P  (64 KB)
  __shared__ float red2[64 * 17 * 2];          // [t][cg] (stride 17) x {s1,s2}
  __shared__ float m_l[64], rs_l[64];
  const int tid = threadIdx.x;
  const int b = blockIdx.y;
  const int t0 = blockIdx.x * 64;
  const float* xb = x + (size_t)b * C_ * T_ + t0;
  const int tp = tid & 31, cg = tid >> 5;      // t-pair 2*tp, col-group cg*32
  const int t2 = tp * 2;

  // pass 1: float2 loads (t-pairs); stats in f32; keep x as packed bf16 (t2|t2+1) in regs
  unsigned int xr[32];
  {
    float s1a = 0.f, s2a = 0.f, s1b = 0.f, s2b = 0.f;
    #pragma unroll
    for (int j = 0; j < 32; j++){
      int c = cg * 32 + j;
      float2 v = *(const float2*)&xb[(size_t)c * T_ + t2];
      s1a += v.x; s2a += v.x * v.x;
      s1b += v.y; s2b += v.y * v.y;
      xr[j] = (unsigned)f2bf(v.x) | ((unsigned)f2bf(v.y) << 16);
    }
    red2[(t2 * 17 + cg) * 2 + 0] = s1a;
    red2[(t2 * 17 + cg) * 2 + 1] = s2a;
    red2[((t2 + 1) * 17 + cg) * 2 + 0] = s1b;
    red2[((t2 + 1) * 17 + cg) * 2 + 1] = s2b;
  }
  __syncthreads();
  if (tid < 64){
    float s1 = 0.f, s2 = 0.f;
    #pragma unroll
    for (int j = 0; j < 16; j++){
      s1 += red2[(tid * 17 + j) * 2 + 0];
      s2 += red2[(tid * 17 + j) * 2 + 1];
    }
    float m = s1 * (1.0f / 512.0f);
    float var = s2 * (1.0f / 512.0f) - m * m;
    m_l[tid] = m;
    rs_l[tid] = rsqrtf(var + 1e-5f);
  }
  __syncthreads();
  // pass 2: LN from registers -> bf16 A tile rows t2 and t2+1 (XOR-swizzled rows)
  {
    float m0 = m_l[t2], rs0 = rs_l[t2];
    float m1 = m_l[t2 + 1], rs1 = rs_l[t2 + 1];
    #pragma unroll
    for (int o = 0; o < 4; o++){
      int c0 = cg * 32 + o * 8;
      bf16x8 av0, av1;
      #pragma unroll
      for (int j = 0; j < 8; j++){
        unsigned u = xr[o * 8 + j];
        int c = c0 + j;
        float gv = g[c], bv2 = bl[c];
        av0[j] = (short)f2bf((bf2f((unsigned short)(u & 0xffffu)) - m0) * rs0 * gv + bv2);
        av1[j] = (short)f2bf((bf2f((unsigned short)(u >> 16)) - m1) * rs1 * gv + bv2);
      }
      *(bf16x8*)&a_lds[(t2 * 512 + c0) ^ ((t2 & 7) << 3)] = av0;
      *(bf16x8*)&a_lds[((t2 + 1) * 512 + c0) ^ (((t2 + 1) & 7) << 3)] = av1;
    }
  }
  __syncthreads();

  const int w = tid >> 6, ln = tid & 63, lc = ln & 15, lk = ln >> 4;
  const int wr = w >> 2, wc = w & 3;
  // ---- Q GEMM: per wave M=32 (t-half wr), N=128 (slice wc), K=512 ----
  f32x4 acc[2][8];
  #pragma unroll
  for (int i = 0; i < 2; i++)
    #pragma unroll
    for (int j = 0; j < 8; j++) acc[i][j] = (f32x4){0.f, 0.f, 0.f, 0.f};
  const bf16x8* wqv = (const bf16x8*)wq_pk;
  bf16x8 bbuf[2][8];
  #pragma unroll
  for (int nt = 0; nt < 8; nt++) bbuf[0][nt] = wqv[(size_t)(wc * 8 + nt) * 64 + ln];
  #pragma unroll
  for (int kk = 0; kk < 16; kk++){
    int cur = kk & 1, nxt = cur ^ 1;
    if (kk < 15){
      #pragma unroll
      for (int nt = 0; nt < 8; nt++)
        bbuf[nxt][nt] = wqv[(size_t)((kk + 1) * 32 + wc * 8 + nt) * 64 + ln];
    }
    bf16x8 af[2];
    #pragma unroll
    for (int mt = 0; mt < 2; mt++){
      int tr = wr * 32 + mt * 16 + lc;
      af[mt] = *(const bf16x8*)&a_lds[(tr * 512 + kk * 32 + lk * 8) ^ ((tr & 7) << 3)];
    }
    #pragma unroll
    for (int mt = 0; mt < 2; mt++)
      #pragma unroll
      for (int nt = 0; nt < 8; nt++)
        acc[mt][nt] = __builtin_amdgcn_mfma_f32_16x16x32_bf16(af[mt], bbuf[cur][nt], acc[mt][nt], 0, 0, 0);
  }
  // attn fragments (A-operand of attn^T in the PV^T step); heads 2*wc, 2*wc+1
  bf16x8 b2[2][2][4];
  const bf16x8* apk = (const bf16x8*)attn_pk;
  #pragma unroll
  for (int hh = 0; hh < 2; hh++)
    #pragma unroll
    for (int k2 = 0; k2 < 2; k2++)
      #pragma unroll
      for (int np = 0; np < 4; np++)
        b2[hh][k2][np] = apk[((size_t)(b * 8 + (2 * wc + hh)) * 512 + (k2 * 4 + np) * 64 + ln)];
  // bias + per-head softmax over D=64
  float bqv[8];
  #pragma unroll
  for (int nt = 0; nt < 8; nt++) bqv[nt] = bq[wc * 128 + nt * 16 + lc];
  #pragma unroll
  for (int mt = 0; mt < 2; mt++)
    #pragma unroll
    for (int r = 0; r < 4; r++)
      #pragma unroll
      for (int h2 = 0; h2 < 2; h2++){
        float v[4];
        #pragma unroll
        for (int j = 0; j < 4; j++) v[j] = acc[mt][h2 * 4 + j][r] + bqv[h2 * 4 + j];
        float mx = fmaxf(fmaxf(v[0], v[1]), fmaxf(v[2], v[3]));
        #pragma unroll
        for (int o = 1; o < 16; o <<= 1) mx = fmaxf(mx, __shfl_xor(mx, o));
        float e[4], s = 0.f;
        #pragma unroll
        for (int j = 0; j < 4; j++){ e[j] = expf(v[j] - mx); s += e[j]; }
        #pragma unroll
        for (int o = 1; o < 16; o <<= 1) s += __shfl_xor(s, o);
        float inv = 1.0f / s;
        #pragma unroll
        for (int j = 0; j < 4; j++) acc[mt][h2 * 4 + j][r] = e[j] * inv;
      }
  __syncthreads();                 // A-tile reads complete
  // store P (bf16) into a_lds (same swizzle): rows wr*32+..., cols wc*128+...
  #pragma unroll
  for (int mt = 0; mt < 2; mt++)
    #pragma unroll
    for (int r = 0; r < 4; r++){
      int tr = wr * 32 + mt * 16 + lk * 4 + r;
      #pragma unroll
      for (int nt = 0; nt < 8; nt++){
        int col = wc * 128 + nt * 16 + lc;
        a_lds[(tr * 512 + col) ^ ((tr & 7) << 3)] = f2bf(acc[mt][nt][r]);
      }
    }
  __syncthreads();
  // ---- PV^T: o^T[c][t] = attn^T (A=b2) @ P^T (B=pb). D: row=c_local, col=t_local ----
  f32x4 acc2[2][4][2];             // [hh][mtc(c)][ntt(t)]
  #pragma unroll
  for (int i = 0; i < 2; i++)
    #pragma unroll
    for (int j = 0; j < 4; j++)
      #pragma unroll
      for (int k = 0; k < 2; k++) acc2[i][j][k] = (f32x4){0.f, 0.f, 0.f, 0.f};
  #pragma unroll
  for (int k2 = 0; k2 < 2; k2++){
    bf16x8 pb[2][2];
    #pragma unroll
    for (int hh = 0; hh < 2; hh++)
      #pragma unroll
      for (int ntt = 0; ntt < 2; ntt++){
        int tr = wr * 32 + ntt * 16 + lc;
        int col = wc * 128 + hh * 64 + k2 * 32 + lk * 8;
        pb[hh][ntt] = *(const bf16x8*)&a_lds[(tr * 512 + col) ^ ((tr & 7) << 3)];
      }
    #pragma unroll
    for (int hh = 0; hh < 2; hh++)
      #pragma unroll
      for (int mtc = 0; mtc < 4; mtc++)
        #pragma unroll
        for (int ntt = 0; ntt < 2; ntt++)
          acc2[hh][mtc][ntt] = __builtin_amdgcn_mfma_f32_16x16x32_bf16(b2[hh][k2][mtc], pb[hh][ntt], acc2[hh][mtc][ntt], 0, 0, 0);
  }
  // ---- epilogue: direct coalesced stores (64B segments), residual from global ----
  #pragma unroll
  for (int hh = 0; hh < 2; hh++)
    #pragma unroll
    for (int mtc = 0; mtc < 4; mtc++)
      #pragma unroll
      for (int ntt = 0; ntt < 2; ntt++)
        #pragma unroll
        for (int r = 0; r < 4; r++){
          int c = wc * 128 + hh * 64 + mtc * 16 + lk * 4 + r;
          int tt2 = wr * 32 + ntt * 16 + lc;
          float xv = xb[(size_t)c * T_ + tt2];
          out[((size_t)b * C_ + c) * T_ + t0 + tt2] = xv + acc2[hh][mtc][ntt][r];
        }
}

extern "C" void kernel_launch(void* const* d_in, const int* in_sizes, int n_in,
                              void* d_out, int out_size, void* d_ws, size_t ws_size,
                              hipStream_t stream) {
  (void)in_sizes; (void)n_in; (void)out_size; (void)ws_size;
  const float* x     = (const float*)d_in[0];
  const float* ctx   = (const float*)d_in[1];
  const int*   mask  = (const int*)d_in[2];
  const float* ln_g  = (const float*)d_in[3];
  const float* ln_b  = (const float*)d_in[4];
  const float* cln_g = (const float*)d_in[5];
  const float* cln_b = (const float*)d_in[6];
  const float* Wq    = (const float*)d_in[7];
  const float* bq    = (const float*)d_in[8];
  const float* Wk    = (const float*)d_in[9];
  const float* bk    = (const float*)d_in[10];
  const float* Wv    = (const float*)d_in[11];
  const float* bv    = (const float*)d_in[12];
  float* out = (float*)d_out;
  char* wsb = (char*)d_ws;
  unsigned short* ctx_nb = (unsigned short*)wsb;                // 3,145,728 B
  unsigned short* wq_pk  = (unsigned short*)(wsb + 3145728);    //   524,288 B
  unsigned short* wkv_pk = (unsigned short*)(wsb + 3670016);    // 1,572,864 B
  unsigned short* apk    = (unsigned short*)(wsb + 5242880);    //   524,288 B

  prep<<<2560, 256, 0, stream>>>(ctx, cln_g, cln_b, Wq, Wk, Wv, ctx_nb, wq_pk, wkv_pk);
  ctx_attn<<<64, 256, 0, stream>>>(ctx_nb, wkv_pk, bk, bv, mask, apk);
  fused_main<<<dim3(T_ / 64, B_), 512, 0, stream>>>(x, ln_g, ln_b, wq_pk, bq, apk, out);
}